// Round 7
// baseline (254.666 us; speedup 1.0000x reference)
//
#include <hip/hip_runtime.h>
#include <hip/hip_bf16.h>
#include <stdint.h>

#define T_TOK 4096
#define H_DIM 2048
#define I_DIM 1024
#define E_NUM 8
#define NPAIR 8192            // T_TOK * K_SEL
#define BM 128
#define MAX_TILES 72          // worst case sum(ceil(cnt_e/128)) = 64 + 7
#define CAP (MAX_TILES * BM)  // 9216 padded pair slots
#define NTB2 (MAX_TILES * 8)  // gemm grid = 576 (8 nt of 256 cols)

// prep_all grid layout
#define CVT_BLKS 1024
#define GU_BLKS 4096          // 8192 gu 64x64 tiles, 2 per block
#define D_BLKS 2048           // 4096 d 64x64 tiles, 2 per block
#define PREP_BLKS (CVT_BLKS + GU_BLKS + D_BLKS + 1)

typedef short s16x8 __attribute__((ext_vector_type(8)));
typedef __bf16 bf16x8 __attribute__((ext_vector_type(8)));
typedef float f32x4 __attribute__((ext_vector_type(4)));

using gas1_t = const __attribute__((address_space(1))) void*;
using las3_t = __attribute__((address_space(3))) void*;

__device__ __forceinline__ void async_lds16(const void* g, void* l) {
  __builtin_amdgcn_global_load_lds((gas1_t)(uintptr_t)g,
                                   (las3_t)(uint32_t)(uintptr_t)l, 16, 0, 0);
}

__device__ __forceinline__ unsigned short f2bf(float f) {
  union { float f; unsigned int u; } v; v.f = f;
  unsigned int r = v.u + 0x7FFF + ((v.u >> 16) & 1); // RNE
  return (unsigned short)(r >> 16);
}

__device__ __forceinline__ f32x4 mfma_bf16(s16x8 a, s16x8 b, f32x4 c) {
  return __builtin_amdgcn_mfma_f32_16x16x32_bf16(
      __builtin_bit_cast(bf16x8, a), __builtin_bit_cast(bf16x8, b), c, 0, 0, 0);
}

__device__ __forceinline__ unsigned short gelu_mul_bf16(float g, float u) {
  const float z = 0.7978845608028654f * (g + 0.044715f * g * g * g);
  const float ex = __expf(2.f * z);
  const float th = (ex - 1.f) / (ex + 1.f);
  return f2bf(0.5f * g * (1.f + th) * u);
}

__device__ __forceinline__ float bflo(unsigned int u) {
  return __uint_as_float(u << 16);
}
__device__ __forceinline__ float bfhi(unsigned int u) {
  return __uint_as_float(u & 0xFFFF0000u);
}

// ===== prep: cvt x + transpose(Wg,Wu->WguT) + transpose(Wd->WdT) + routing ==
// (identical to round-5/6 passing version; LDS stride 73 = conflict-free)
__global__ __launch_bounds__(512)
void prep_all(const float4* __restrict__ x4, ushort4* __restrict__ xb4,
              const float* __restrict__ Wg, const float* __restrict__ Wu,
              const float* __restrict__ Wd,
              unsigned short* __restrict__ WguT,
              unsigned short* __restrict__ WdT,
              const int* __restrict__ sel, const float* __restrict__ rw,
              int* __restrict__ pair_token, float* __restrict__ pair_weight,
              int* __restrict__ inv,
              int* __restrict__ tile_expert, int* __restrict__ tile_pos) {
  const int bid = blockIdx.x;
  const int tid = threadIdx.x;

  if (bid < CVT_BLKS) {                    // ---- cvt x -> bf16 ----
    int i = bid * 512 + tid;
    const int stride = CVT_BLKS * 512;
#pragma unroll
    for (int q = 0; q < 4; ++q) {
      const float4 v = x4[i];
      ushort4 r;
      r.x = f2bf(v.x); r.y = f2bf(v.y); r.z = f2bf(v.z); r.w = f2bf(v.w);
      xb4[i] = r;
      i += stride;
    }
    return;
  }

  if (bid < CVT_BLKS + GU_BLKS + D_BLKS) { // ---- weight transposes ----
    __shared__ unsigned short Tl[2][64 * 73];
    const int sub = tid >> 8, k = tid & 255;
    const int rr = k >> 2, cb = (k & 3) * 16;
    const int oc = k >> 2, rb = (k & 3) * 16;

    if (bid < CVT_BLKS + GU_BLKS) {        // Wg/Wu -> WguT (g/u interleaved)
      const int t3 = (bid - CVT_BLKS) * 2 + sub;    // [0, 8192)
      const int which = t3 >> 12;                   // 0=gate, 1=up
      const int e = (t3 >> 9) & 7;
      const int tile = t3 & 511;                    // 32 h-tiles x 16 i-tiles
      const int r0 = (tile >> 4) * 64;              // h base
      const int c0 = (tile & 15) * 64;              // i base
      const float* src = (which ? Wu : Wg) + (size_t)e * H_DIM * I_DIM;
      const float4* s4 = (const float4*)(src + (size_t)(r0 + rr) * I_DIM + c0 + cb);
      unsigned short* dl = &Tl[sub][rr * 73 + cb];
#pragma unroll
      for (int q = 0; q < 4; ++q) {
        const float4 v = s4[q];
        dl[q * 4 + 0] = f2bf(v.x); dl[q * 4 + 1] = f2bf(v.y);
        dl[q * 4 + 2] = f2bf(v.z); dl[q * 4 + 3] = f2bf(v.w);
      }
      __syncthreads();
      union { unsigned short us[16]; uint4 u4[2]; } pk;
#pragma unroll
      for (int m = 0; m < 16; ++m) pk.us[m] = Tl[sub][(rb + m) * 73 + oc];
      const int gi = c0 + oc;
      const int orow = (gi >> 4) * 32 + (gi & 15) + which * 16;
      uint4* d4 = (uint4*)(WguT + ((size_t)e * 2048 + orow) * H_DIM + r0 + rb);
      d4[0] = pk.u4[0]; d4[1] = pk.u4[1];
    } else {                               // Wd -> WdT (i'-permuted cols)
      const int t3 = (bid - CVT_BLKS - GU_BLKS) * 2 + sub;  // [0, 4096)
      const int e = t3 >> 9;
      const int tile = t3 & 511;                    // 16 i-tiles x 32 h-tiles
      const int r0 = (tile >> 5) * 64;              // i base
      const int c0 = (tile & 31) * 64;              // h base
      const float* src = Wd + (size_t)e * I_DIM * H_DIM;
      const float4* s4 = (const float4*)(src + (size_t)(r0 + rr) * H_DIM + c0 + cb);
      unsigned short* dl = &Tl[sub][rr * 73 + cb];
#pragma unroll
      for (int q = 0; q < 4; ++q) {
        const float4 v = s4[q];
        dl[q * 4 + 0] = f2bf(v.x); dl[q * 4 + 1] = f2bf(v.y);
        dl[q * 4 + 2] = f2bf(v.z); dl[q * 4 + 3] = f2bf(v.w);
      }
      __syncthreads();
      union { unsigned short us[16]; uint4 u4[2]; } pk;
#pragma unroll
      for (int m = 0; m < 16; ++m) {
        const int il = rb + m;                      // i' local [0,64)
        const int isrc = (il & 32) + ((il & 1) << 4) + ((il >> 1) & 15);
        pk.us[m] = Tl[sub][isrc * 73 + oc];
      }
      const int gh = c0 + oc;
      uint4* d4 = (uint4*)(WdT + ((size_t)e * H_DIM + gh) * I_DIM + r0 + rb);
      d4[0] = pk.u4[0]; d4[1] = pk.u4[1];
    }
    return;
  }

  // ---- routing (single block) ----
  __shared__ int cnt[E_NUM], off[E_NUM], fil[E_NUM];
  if (tid < E_NUM) { cnt[tid] = 0; fil[tid] = 0; }
  __syncthreads();
  for (int p = tid; p < NPAIR; p += 512) atomicAdd(&cnt[sel[p]], 1);
  for (int q = tid; q < CAP; q += 512) { pair_token[q] = 0; pair_weight[q] = 0.f; }
  __syncthreads();
  if (tid == 0) {
    int run = 0, idx = 0;
    for (int e = 0; e < E_NUM; ++e) {
      off[e] = run;
      const int nt = (cnt[e] + BM - 1) / BM;
      for (int t = 0; t < nt; ++t) { tile_expert[idx] = e; tile_pos[idx] = run + t * BM; ++idx; }
      run += nt * BM;
    }
    for (; idx < MAX_TILES; ++idx) tile_expert[idx] = -1;
  }
  __syncthreads();
  for (int p = tid; p < NPAIR; p += 512) {
    const int e = sel[p];
    const int pos = off[e] + atomicAdd(&fil[e], 1);
    pair_token[pos] = p >> 1;   // K_SEL == 2
    pair_weight[pos] = rw[p];
    inv[p] = pos;
  }
}

// ================= 128x256 8-wave GEMM, 3-slot ring, counted vmcnt =========
// MODE 0: A = xb gathered by pair_token (K=2048), B = WguT -> a_pair packed u32
// MODE 1: A = a_pair (K=1024, i' order), B = WdT -> d_pair bf16 (w applied)
// L2-locality mapping: nt = bid & 7 = XCD id (round-robin dispatch), so each
// XCD works on ONE fixed 256-col B band and sweeps mt in expert order. Its 32
// CUs span ~4 experts x 1MB B-slice = 4MB = L2-resident -> B staging becomes
// L2-hit instead of streaming the L3 fabric (the 6.8 TB/s wall of r4-r6).
template<int MODE>
__global__ __launch_bounds__(512, 2)
void moe_gemm(const unsigned short* __restrict__ Aop,
              const unsigned short* __restrict__ Bop,
              const int* __restrict__ pair_token,
              const float* __restrict__ pair_weight,
              const int* __restrict__ tile_expert,
              const int* __restrict__ tile_pos,
              unsigned int* __restrict__ a32,
              unsigned short* __restrict__ d_pair) {
  constexpr int KD = (MODE == 0) ? H_DIM : I_DIM;
  constexpr int NT = KD / 64;

  extern __shared__ unsigned short smem[];
  unsigned short* sA = smem;             // 3 slots x 8192 shorts
  unsigned short* sB = smem + 3 * 8192;  // 3 slots x 16384 shorts

  const int bid = blockIdx.x;
  const int mt = bid >> 3;               // mt sweeps within each XCD
  const int nt = bid & 7;                // nt == XCD id: fixed B band per XCD
  const int e = tile_expert[mt];
  if (e < 0) return;
  const int pbase = tile_pos[mt];

  const int tid = threadIdx.x;
  const int wv = tid >> 6;               // 0..7
  const int lane = tid & 63;
  const int fr = lane & 15;
  const int fq = lane >> 4;
  const int wm = (wv >> 2) * 64;         // 0/64
  const int wn = (wv & 3) * 64;          // 0/64/128/192

  // staging source pointers (pre-swizzled 16B chunks)
  const int rloc = lane >> 3;            // 0..7
  const int gch = (lane & 7) ^ rloc;     // row&7 == rloc for every op
  const unsigned short* pa[2];
  const unsigned short* pb[4];
#pragma unroll
  for (int j = 0; j < 2; ++j) {
    const int row = j * 64 + wv * 8 + rloc;   // 0..127
    size_t arow;
    if constexpr (MODE == 0) arow = (size_t)pair_token[pbase + row];
    else                     arow = (size_t)(pbase + row);
    pa[j] = Aop + arow * KD + gch * 8;
  }
#pragma unroll
  for (int j = 0; j < 4; ++j) {
    const int row = j * 64 + wv * 8 + rloc;   // 0..255
    pb[j] = Bop + ((size_t)e * 2048 + nt * 256 + row) * KD + gch * 8;
  }

  // LDS fragment offsets (shorts); row stride = 64 shorts, XOR chunk swizzle
  int aoff[4][2], boff[4][2];
#pragma unroll
  for (int f = 0; f < 4; ++f)
#pragma unroll
    for (int kk = 0; kk < 2; ++kk) {
      const int ra = wm + f * 16 + fr;
      aoff[f][kk] = ra * 64 + (((kk * 4 + fq) ^ (ra & 7)) * 8);
      const int rb = wn + f * 16 + fr;
      boff[f][kk] = rb * 64 + (((kk * 4 + fq) ^ (rb & 7)) * 8);
    }

  f32x4 acc[4][4] = {};

#define STAGE_A(T, S)                                                        \
  {                                                                          \
    unsigned short* _d = sA + (S) * 8192 + wv * 512;                         \
    _Pragma("unroll")                                                        \
    for (int j = 0; j < 2; ++j)                                              \
      async_lds16(pa[j] + (size_t)(T) * 64, _d + j * 4096);                  \
  }
#define STAGE_B(T, S)                                                        \
  {                                                                          \
    unsigned short* _d = sB + (S) * 16384 + wv * 512;                        \
    _Pragma("unroll")                                                        \
    for (int j = 0; j < 4; ++j)                                              \
      async_lds16(pb[j] + (size_t)(T) * 64, _d + j * 4096);                  \
  }

  // prologue: slot0 = tile0, slot1 = tile1; wait for slot0 (6 newest remain)
  STAGE_A(0, 0); STAGE_B(0, 0);
  STAGE_A(1, 1); STAGE_B(1, 1);
  asm volatile("s_waitcnt vmcnt(6)" ::: "memory");
  __builtin_amdgcn_s_barrier();

  int s = 0, s2 = 2;
  for (int t = 0; t < NT; ++t) {
    const unsigned short* As = sA + s * 8192;
    const unsigned short* Bs = sB + s * 16384;
    s16x8 aF[2][2], bF[4][2];
    // ---- P0: read B all + A rows wm..wm+31; stage A(t+2)
#pragma unroll
    for (int nf = 0; nf < 4; ++nf)
#pragma unroll
      for (int kk = 0; kk < 2; ++kk)
        bF[nf][kk] = *(const s16x8*)&Bs[boff[nf][kk]];
#pragma unroll
    for (int mf = 0; mf < 2; ++mf)
#pragma unroll
      for (int kk = 0; kk < 2; ++kk)
        aF[mf][kk] = *(const s16x8*)&As[aoff[mf][kk]];
    if (t + 2 < NT) STAGE_A(t + 2, s2);
    __builtin_amdgcn_s_barrier();
    __builtin_amdgcn_s_setprio(1);
#pragma unroll
    for (int kk = 0; kk < 2; ++kk)
#pragma unroll
      for (int mf = 0; mf < 2; ++mf)
#pragma unroll
        for (int nf = 0; nf < 4; ++nf)
          acc[mf][nf] = mfma_bf16(aF[mf][kk], bF[nf][kk], acc[mf][nf]);
    __builtin_amdgcn_s_setprio(0);
    __builtin_amdgcn_s_barrier();
    // ---- P1: read A rows wm+32..wm+63; stage B(t+2); counted vmcnt
    s16x8 aG[2][2];
#pragma unroll
    for (int mf = 0; mf < 2; ++mf)
#pragma unroll
      for (int kk = 0; kk < 2; ++kk)
        aG[mf][kk] = *(const s16x8*)&As[aoff[2 + mf][kk]];
    if (t + 2 < NT) {
      STAGE_B(t + 2, s2);
      asm volatile("s_waitcnt vmcnt(6)" ::: "memory");  // slot t+1 resident
    } else if (t + 1 < NT) {
      asm volatile("s_waitcnt vmcnt(0)" ::: "memory");  // drain last slot
    }
    __builtin_amdgcn_s_barrier();
    __builtin_amdgcn_s_setprio(1);
#pragma unroll
    for (int kk = 0; kk < 2; ++kk)
#pragma unroll
      for (int mf = 0; mf < 2; ++mf)
#pragma unroll
        for (int nf = 0; nf < 4; ++nf)
          acc[2 + mf][nf] = mfma_bf16(aG[mf][kk], bF[nf][kk], acc[2 + mf][nf]);
    __builtin_amdgcn_s_setprio(0);
    __builtin_amdgcn_s_barrier();
    s = (s == 2) ? 0 : s + 1;
    s2 = (s2 == 2) ? 0 : s2 + 1;
  }
#undef STAGE_A
#undef STAGE_B

  if constexpr (MODE == 0) {
    // packed epilogue: (nf0,nf1)=(g,u) of i, (nf2,nf3)=(g,u) of i+16
    const int cidx = (nt * 4 + (wn >> 6)) * 16 + fr;   // dword index in row
#pragma unroll
    for (int mf = 0; mf < 4; ++mf)
#pragma unroll
      for (int jj = 0; jj < 4; ++jj) {
        const int row = pbase + wm + mf * 16 + fq * 4 + jj;
        const unsigned int h0 = gelu_mul_bf16(acc[mf][0][jj], acc[mf][1][jj]);
        const unsigned int h1 = gelu_mul_bf16(acc[mf][2][jj], acc[mf][3][jj]);
        a32[(size_t)row * (I_DIM / 2) + cidx] = h0 | (h1 << 16);
      }
  } else {
    // plain bf16 stores of w*d into d_pair (combine sums the two experts)
#pragma unroll
    for (int mf = 0; mf < 4; ++mf)
#pragma unroll
      for (int jj = 0; jj < 4; ++jj) {
        const int prow = pbase + wm + mf * 16 + fq * 4 + jj;
        const float w = pair_weight[prow];
        unsigned short* dp = d_pair + (size_t)prow * H_DIM + nt * 256 + wn + fr;
#pragma unroll
        for (int nf = 0; nf < 4; ++nf)
          dp[nf * 16] = f2bf(w * acc[mf][nf][jj]);
      }
  }
}

// ========================= combine: out[t] = d[p0] + d[p1] =================
__global__ __launch_bounds__(256)
void combine(const unsigned short* __restrict__ d_pair,
             const int* __restrict__ inv,
             float* __restrict__ out) {
  const int tid = threadIdx.x;
  const int tok = blockIdx.x * 2 + (tid >> 7);
  const int ln = tid & 127;
  const int p0 = inv[2 * tok], p1 = inv[2 * tok + 1];
  const uint4* r0 = (const uint4*)(d_pair + (size_t)p0 * H_DIM);
  const uint4* r1 = (const uint4*)(d_pair + (size_t)p1 * H_DIM);
  float4* o = (float4*)(out + (size_t)tok * H_DIM);
#pragma unroll
  for (int j = 0; j < 2; ++j) {
    const int c = ln + j * 128;               // uint4 index, 256 per row
    const uint4 a = r0[c];
    const uint4 b = r1[c];
    float4 fa, fb;
    fa.x = bflo(a.x) + bflo(b.x); fa.y = bfhi(a.x) + bfhi(b.x);
    fa.z = bflo(a.y) + bflo(b.y); fa.w = bfhi(a.y) + bfhi(b.y);
    fb.x = bflo(a.z) + bflo(b.z); fb.y = bfhi(a.z) + bfhi(b.z);
    fb.z = bflo(a.w) + bflo(b.w); fb.w = bfhi(a.w) + bfhi(b.w);
    o[2 * c] = fa;
    o[2 * c + 1] = fb;
  }
}

// ================================= launch ==================================
extern "C" void kernel_launch(void* const* d_in, const int* in_sizes, int n_in,
                              void* d_out, int out_size, void* d_ws, size_t ws_size,
                              hipStream_t stream) {
  const float* x  = (const float*)d_in[0];
  const float* Wg = (const float*)d_in[1];
  const float* Wu = (const float*)d_in[2];
  const float* Wd = (const float*)d_in[3];
  const int*   sel = (const int*)d_in[4];
  const float* rw  = (const float*)d_in[5];
  float* out = (float*)d_out;

  char* base = (char*)d_ws;
  size_t off = 0;
  auto take = [&](size_t bytes) { char* p = base + off; off += bytes; return p; };
  unsigned short* xb     = (unsigned short*)take((size_t)T_TOK * H_DIM * 2);
  unsigned short* WguT   = (unsigned short*)take((size_t)E_NUM * 2048 * H_DIM * 2);
  unsigned short* WdT    = (unsigned short*)take((size_t)E_NUM * H_DIM * I_DIM * 2);
  unsigned short* a_pair = (unsigned short*)take((size_t)CAP * I_DIM * 2);
  unsigned short* d_pair = (unsigned short*)take((size_t)CAP * H_DIM * 2);
  int*   pair_token  = (int*)take(CAP * 4);
  float* pair_weight = (float*)take(CAP * 4);
  int*   inv         = (int*)take(NPAIR * 4);
  int*   tile_expert = (int*)take(512);
  int*   tile_pos    = (int*)take(512);
  (void)off;

  hipFuncSetAttribute((const void*)&moe_gemm<0>,
                      hipFuncAttributeMaxDynamicSharedMemorySize, 147456);
  hipFuncSetAttribute((const void*)&moe_gemm<1>,
                      hipFuncAttributeMaxDynamicSharedMemorySize, 147456);

  prep_all<<<PREP_BLKS, 512, 0, stream>>>(
      (const float4*)x, (ushort4*)xb, Wg, Wu, Wd, WguT, WdT, sel, rw,
      pair_token, pair_weight, inv, tile_expert, tile_pos);

  moe_gemm<0><<<NTB2, 512, 147456, stream>>>(
      xb, WguT, pair_token, pair_weight, tile_expert, tile_pos,
      (unsigned int*)a_pair, nullptr);

  moe_gemm<1><<<NTB2, 512, 147456, stream>>>(
      a_pair, WdT, pair_token, pair_weight, tile_expert, tile_pos,
      nullptr, d_pair);

  combine<<<T_TOK / 2, 256, 0, stream>>>(d_pair, inv, out);
}

// Round 8
// 251.412 us; speedup vs baseline: 1.0129x; 1.0129x over previous
//
#include <hip/hip_runtime.h>
#include <hip/hip_bf16.h>
#include <stdint.h>

#define T_TOK 4096
#define H_DIM 2048
#define I_DIM 1024
#define E_NUM 8
#define NPAIR 8192            // T_TOK * K_SEL
#define BM 128
#define MAX_TILES 72          // worst case sum(ceil(cnt_e/128)) = 64 + 7
#define CAP (MAX_TILES * BM)  // 9216 padded pair slots
#define NTB2 (MAX_TILES * 8)  // gemm grid = 576 (8 nt of 256 cols)

// prep_all grid layout
#define CVT_BLKS 1024
#define GU_BLKS 4096          // 8192 gu 64x64 tiles, 2 per block
#define D_BLKS 2048           // 4096 d 64x64 tiles, 2 per block
#define PREP_BLKS (CVT_BLKS + GU_BLKS + D_BLKS + 1)

typedef short s16x8 __attribute__((ext_vector_type(8)));
typedef __bf16 bf16x8 __attribute__((ext_vector_type(8)));
typedef float f32x4 __attribute__((ext_vector_type(4)));

using gas1_t = const __attribute__((address_space(1))) void*;
using las3_t = __attribute__((address_space(3))) void*;

__device__ __forceinline__ void async_lds16(const void* g, void* l) {
  __builtin_amdgcn_global_load_lds((gas1_t)(uintptr_t)g,
                                   (las3_t)(uint32_t)(uintptr_t)l, 16, 0, 0);
}

__device__ __forceinline__ unsigned short f2bf(float f) {
  union { float f; unsigned int u; } v; v.f = f;
  unsigned int r = v.u + 0x7FFF + ((v.u >> 16) & 1); // RNE
  return (unsigned short)(r >> 16);
}

__device__ __forceinline__ f32x4 mfma_bf16(s16x8 a, s16x8 b, f32x4 c) {
  return __builtin_amdgcn_mfma_f32_16x16x32_bf16(
      __builtin_bit_cast(bf16x8, a), __builtin_bit_cast(bf16x8, b), c, 0, 0, 0);
}

__device__ __forceinline__ unsigned short gelu_mul_bf16(float g, float u) {
  const float z = 0.7978845608028654f * (g + 0.044715f * g * g * g);
  const float ex = __expf(2.f * z);
  const float th = (ex - 1.f) / (ex + 1.f);
  return f2bf(0.5f * g * (1.f + th) * u);
}

__device__ __forceinline__ float bflo(unsigned int u) {
  return __uint_as_float(u << 16);
}
__device__ __forceinline__ float bfhi(unsigned int u) {
  return __uint_as_float(u & 0xFFFF0000u);
}

// ===== prep: cvt x + transpose(Wg,Wu->WguT) + transpose(Wd->WdT) + routing ==
// (identical to round-5/6/7 passing version; LDS stride 73 = conflict-free)
__global__ __launch_bounds__(512)
void prep_all(const float4* __restrict__ x4, ushort4* __restrict__ xb4,
              const float* __restrict__ Wg, const float* __restrict__ Wu,
              const float* __restrict__ Wd,
              unsigned short* __restrict__ WguT,
              unsigned short* __restrict__ WdT,
              const int* __restrict__ sel, const float* __restrict__ rw,
              int* __restrict__ pair_token, float* __restrict__ pair_weight,
              int* __restrict__ inv,
              int* __restrict__ tile_expert, int* __restrict__ tile_pos) {
  const int bid = blockIdx.x;
  const int tid = threadIdx.x;

  if (bid < CVT_BLKS) {                    // ---- cvt x -> bf16 ----
    int i = bid * 512 + tid;
    const int stride = CVT_BLKS * 512;
#pragma unroll
    for (int q = 0; q < 4; ++q) {
      const float4 v = x4[i];
      ushort4 r;
      r.x = f2bf(v.x); r.y = f2bf(v.y); r.z = f2bf(v.z); r.w = f2bf(v.w);
      xb4[i] = r;
      i += stride;
    }
    return;
  }

  if (bid < CVT_BLKS + GU_BLKS + D_BLKS) { // ---- weight transposes ----
    __shared__ unsigned short Tl[2][64 * 73];
    const int sub = tid >> 8, k = tid & 255;
    const int rr = k >> 2, cb = (k & 3) * 16;
    const int oc = k >> 2, rb = (k & 3) * 16;

    if (bid < CVT_BLKS + GU_BLKS) {        // Wg/Wu -> WguT (g/u interleaved)
      const int t3 = (bid - CVT_BLKS) * 2 + sub;    // [0, 8192)
      const int which = t3 >> 12;                   // 0=gate, 1=up
      const int e = (t3 >> 9) & 7;
      const int tile = t3 & 511;                    // 32 h-tiles x 16 i-tiles
      const int r0 = (tile >> 4) * 64;              // h base
      const int c0 = (tile & 15) * 64;              // i base
      const float* src = (which ? Wu : Wg) + (size_t)e * H_DIM * I_DIM;
      const float4* s4 = (const float4*)(src + (size_t)(r0 + rr) * I_DIM + c0 + cb);
      unsigned short* dl = &Tl[sub][rr * 73 + cb];
#pragma unroll
      for (int q = 0; q < 4; ++q) {
        const float4 v = s4[q];
        dl[q * 4 + 0] = f2bf(v.x); dl[q * 4 + 1] = f2bf(v.y);
        dl[q * 4 + 2] = f2bf(v.z); dl[q * 4 + 3] = f2bf(v.w);
      }
      __syncthreads();
      union { unsigned short us[16]; uint4 u4[2]; } pk;
#pragma unroll
      for (int m = 0; m < 16; ++m) pk.us[m] = Tl[sub][(rb + m) * 73 + oc];
      const int gi = c0 + oc;
      const int orow = (gi >> 4) * 32 + (gi & 15) + which * 16;
      uint4* d4 = (uint4*)(WguT + ((size_t)e * 2048 + orow) * H_DIM + r0 + rb);
      d4[0] = pk.u4[0]; d4[1] = pk.u4[1];
    } else {                               // Wd -> WdT (i'-permuted cols)
      const int t3 = (bid - CVT_BLKS - GU_BLKS) * 2 + sub;  // [0, 4096)
      const int e = t3 >> 9;
      const int tile = t3 & 511;                    // 16 i-tiles x 32 h-tiles
      const int r0 = (tile >> 5) * 64;              // i base
      const int c0 = (tile & 31) * 64;              // h base
      const float* src = Wd + (size_t)e * I_DIM * H_DIM;
      const float4* s4 = (const float4*)(src + (size_t)(r0 + rr) * H_DIM + c0 + cb);
      unsigned short* dl = &Tl[sub][rr * 73 + cb];
#pragma unroll
      for (int q = 0; q < 4; ++q) {
        const float4 v = s4[q];
        dl[q * 4 + 0] = f2bf(v.x); dl[q * 4 + 1] = f2bf(v.y);
        dl[q * 4 + 2] = f2bf(v.z); dl[q * 4 + 3] = f2bf(v.w);
      }
      __syncthreads();
      union { unsigned short us[16]; uint4 u4[2]; } pk;
#pragma unroll
      for (int m = 0; m < 16; ++m) {
        const int il = rb + m;                      // i' local [0,64)
        const int isrc = (il & 32) + ((il & 1) << 4) + ((il >> 1) & 15);
        pk.us[m] = Tl[sub][isrc * 73 + oc];
      }
      const int gh = c0 + oc;
      uint4* d4 = (uint4*)(WdT + ((size_t)e * H_DIM + gh) * I_DIM + r0 + rb);
      d4[0] = pk.u4[0]; d4[1] = pk.u4[1];
    }
    return;
  }

  // ---- routing (single block) ----
  __shared__ int cnt[E_NUM], off[E_NUM], fil[E_NUM];
  if (tid < E_NUM) { cnt[tid] = 0; fil[tid] = 0; }
  __syncthreads();
  for (int p = tid; p < NPAIR; p += 512) atomicAdd(&cnt[sel[p]], 1);
  for (int q = tid; q < CAP; q += 512) { pair_token[q] = 0; pair_weight[q] = 0.f; }
  __syncthreads();
  if (tid == 0) {
    int run = 0, idx = 0;
    for (int e = 0; e < E_NUM; ++e) {
      off[e] = run;
      const int nt = (cnt[e] + BM - 1) / BM;
      for (int t = 0; t < nt; ++t) { tile_expert[idx] = e; tile_pos[idx] = run + t * BM; ++idx; }
      run += nt * BM;
    }
    for (; idx < MAX_TILES; ++idx) tile_expert[idx] = -1;
  }
  __syncthreads();
  for (int p = tid; p < NPAIR; p += 512) {
    const int e = sel[p];
    const int pos = off[e] + atomicAdd(&fil[e], 1);
    pair_token[pos] = p >> 1;   // K_SEL == 2
    pair_weight[pos] = rw[p];
    inv[p] = pos;
  }
}

// ====== 128x256 8-wave GEMM, 3-slot ring, 4-phase micro-interleave =========
// MODE 0: A = xb gathered by pair_token (K=2048), B = WguT -> a_pair packed u32
// MODE 1: A = a_pair (K=1024, i' order), B = WdT -> d_pair bf16 (w applied)
// Per K-step, 4 phases, each {<=6 ds_read + <=2 global_load_lds -> barrier ->
// lgkmcnt(0)+sched_barrier -> 8 MFMA (setprio) -> barrier}; one counted
// vmcnt(6) per K-step (PH3). This is the m201/m196 fine-interleave that lifts
// the global_load_lds feed rate (our r4-r7 invariant: 11 B/cyc/CU -> ~25%
// MfmaUtil at this tile's required 39.6 B/cyc).
template<int MODE>
__global__ __launch_bounds__(512, 2)
void moe_gemm(const unsigned short* __restrict__ Aop,
              const unsigned short* __restrict__ Bop,
              const int* __restrict__ pair_token,
              const float* __restrict__ pair_weight,
              const int* __restrict__ tile_expert,
              const int* __restrict__ tile_pos,
              unsigned int* __restrict__ a32,
              unsigned short* __restrict__ d_pair) {
  constexpr int KD = (MODE == 0) ? H_DIM : I_DIM;
  constexpr int NT = KD / 64;

  extern __shared__ unsigned short smem[];
  unsigned short* sA = smem;             // 3 slots x 8192 shorts
  unsigned short* sB = smem + 3 * 8192;  // 3 slots x 16384 shorts

  const int bid = blockIdx.x;
  const int mt = bid >> 3;               // mt sweeps within each XCD
  const int nt = bid & 7;                // nt == XCD id (round-robin dispatch)
  const int e = tile_expert[mt];
  if (e < 0) return;
  const int pbase = tile_pos[mt];

  const int tid = threadIdx.x;
  const int wv = tid >> 6;               // 0..7
  const int lane = tid & 63;
  const int fr = lane & 15;
  const int fq = lane >> 4;
  const int wm = (wv >> 2) * 64;         // 0/64
  const int wn = (wv & 3) * 64;          // 0/64/128/192

  // staging source pointers (pre-swizzled 16B chunks)
  const int rloc = lane >> 3;            // 0..7
  const int gch = (lane & 7) ^ rloc;     // row&7 == rloc for every op
  const unsigned short* pa[2];
  const unsigned short* pb[4];
#pragma unroll
  for (int j = 0; j < 2; ++j) {
    const int row = j * 64 + wv * 8 + rloc;   // 0..127
    size_t arow;
    if constexpr (MODE == 0) arow = (size_t)pair_token[pbase + row];
    else                     arow = (size_t)(pbase + row);
    pa[j] = Aop + arow * KD + gch * 8;
  }
#pragma unroll
  for (int j = 0; j < 4; ++j) {
    const int row = j * 64 + wv * 8 + rloc;   // 0..255
    pb[j] = Bop + ((size_t)e * 2048 + nt * 256 + row) * KD + gch * 8;
  }

  // LDS fragment offsets (shorts); row stride = 64 shorts, XOR chunk swizzle
  int aoff[4][2], boff[4][2];
#pragma unroll
  for (int f = 0; f < 4; ++f)
#pragma unroll
    for (int kk = 0; kk < 2; ++kk) {
      const int ra = wm + f * 16 + fr;
      aoff[f][kk] = ra * 64 + (((kk * 4 + fq) ^ (ra & 7)) * 8);
      const int rb = wn + f * 16 + fr;
      boff[f][kk] = rb * 64 + (((kk * 4 + fq) ^ (rb & 7)) * 8);
    }

  f32x4 acc[4][4] = {};

#define STAGE_A(T, S)                                                        \
  {                                                                          \
    unsigned short* _d = sA + (S) * 8192 + wv * 512;                         \
    _Pragma("unroll")                                                        \
    for (int j = 0; j < 2; ++j)                                              \
      async_lds16(pa[j] + (size_t)(T) * 64, _d + j * 4096);                  \
  }
#define STAGE_B2(T, S, J0)                                                   \
  {                                                                          \
    unsigned short* _d = sB + (S) * 16384 + wv * 512;                        \
    _Pragma("unroll")                                                        \
    for (int j = (J0); j < (J0) + 2; ++j)                                    \
      async_lds16(pb[j] + (size_t)(T) * 64, _d + j * 4096);                  \
  }

  // prologue: slot0 = tile0, slot1 = tile1; wait for tile0 (6 newest remain)
  STAGE_A(0, 0); STAGE_B2(0, 0, 0); STAGE_B2(0, 0, 2);
  STAGE_A(1, 1); STAGE_B2(1, 1, 0); STAGE_B2(1, 1, 2);
  asm volatile("s_waitcnt vmcnt(6)" ::: "memory");
  __builtin_amdgcn_s_barrier();

  int s = 0, s2 = 2;
  for (int t = 0; t < NT; ++t) {
    const unsigned short* As = sA + s * 8192;
    const unsigned short* Bs = sB + s * 16384;
    const bool pre = (t + 2 < NT);
    s16x8 aF[2][2], aG[2][2], bF[4][2];

    // ---- PH0: read B[*][kk0] (4) + A01[kk0] (2); stage A(t+2)
#pragma unroll
    for (int nf = 0; nf < 4; ++nf) bF[nf][0] = *(const s16x8*)&Bs[boff[nf][0]];
#pragma unroll
    for (int mf = 0; mf < 2; ++mf) aF[mf][0] = *(const s16x8*)&As[aoff[mf][0]];
    if (pre) STAGE_A(t + 2, s2);
    __builtin_amdgcn_s_barrier();
    asm volatile("s_waitcnt lgkmcnt(0)" ::: "memory");
    __builtin_amdgcn_sched_barrier(0);
    __builtin_amdgcn_s_setprio(1);
#pragma unroll
    for (int mf = 0; mf < 2; ++mf)
#pragma unroll
      for (int nf = 0; nf < 4; ++nf)
        acc[mf][nf] = mfma_bf16(aF[mf][0], bF[nf][0], acc[mf][nf]);
    __builtin_amdgcn_s_setprio(0);
    __builtin_amdgcn_s_barrier();

    // ---- PH1: read A23[kk0] (2); stage B(t+2) rows 0..127
#pragma unroll
    for (int mf = 0; mf < 2; ++mf) aG[mf][0] = *(const s16x8*)&As[aoff[2 + mf][0]];
    if (pre) STAGE_B2(t + 2, s2, 0);
    __builtin_amdgcn_s_barrier();
    asm volatile("s_waitcnt lgkmcnt(0)" ::: "memory");
    __builtin_amdgcn_sched_barrier(0);
    __builtin_amdgcn_s_setprio(1);
#pragma unroll
    for (int mf = 0; mf < 2; ++mf)
#pragma unroll
      for (int nf = 0; nf < 4; ++nf)
        acc[2 + mf][nf] = mfma_bf16(aG[mf][0], bF[nf][0], acc[2 + mf][nf]);
    __builtin_amdgcn_s_setprio(0);
    __builtin_amdgcn_s_barrier();

    // ---- PH2: read B[*][kk1] (4) + A01[kk1] (2); stage B(t+2) rows 128..255
#pragma unroll
    for (int nf = 0; nf < 4; ++nf) bF[nf][1] = *(const s16x8*)&Bs[boff[nf][1]];
#pragma unroll
    for (int mf = 0; mf < 2; ++mf) aF[mf][1] = *(const s16x8*)&As[aoff[mf][1]];
    if (pre) STAGE_B2(t + 2, s2, 2);
    __builtin_amdgcn_s_barrier();
    asm volatile("s_waitcnt lgkmcnt(0)" ::: "memory");
    __builtin_amdgcn_sched_barrier(0);
    __builtin_amdgcn_s_setprio(1);
#pragma unroll
    for (int mf = 0; mf < 2; ++mf)
#pragma unroll
      for (int nf = 0; nf < 4; ++nf)
        acc[mf][nf] = mfma_bf16(aF[mf][1], bF[nf][1], acc[mf][nf]);
    __builtin_amdgcn_s_setprio(0);
    __builtin_amdgcn_s_barrier();

    // ---- PH3: read A23[kk1] (2); counted vmcnt (tile t+1 resident)
#pragma unroll
    for (int mf = 0; mf < 2; ++mf) aG[mf][1] = *(const s16x8*)&As[aoff[2 + mf][1]];
    if (pre)                asm volatile("s_waitcnt vmcnt(6)" ::: "memory");
    else if (t + 1 < NT)    asm volatile("s_waitcnt vmcnt(0)" ::: "memory");
    __builtin_amdgcn_s_barrier();
    asm volatile("s_waitcnt lgkmcnt(0)" ::: "memory");
    __builtin_amdgcn_sched_barrier(0);
    __builtin_amdgcn_s_setprio(1);
#pragma unroll
    for (int mf = 0; mf < 2; ++mf)
#pragma unroll
      for (int nf = 0; nf < 4; ++nf)
        acc[2 + mf][nf] = mfma_bf16(aG[mf][1], bF[nf][1], acc[2 + mf][nf]);
    __builtin_amdgcn_s_setprio(0);
    __builtin_amdgcn_s_barrier();

    s = (s == 2) ? 0 : s + 1;
    s2 = (s2 == 2) ? 0 : s2 + 1;
  }
#undef STAGE_A
#undef STAGE_B2

  if constexpr (MODE == 0) {
    // packed epilogue: (nf0,nf1)=(g,u) of i, (nf2,nf3)=(g,u) of i+16
    const int cidx = (nt * 4 + (wn >> 6)) * 16 + fr;   // dword index in row
#pragma unroll
    for (int mf = 0; mf < 4; ++mf)
#pragma unroll
      for (int jj = 0; jj < 4; ++jj) {
        const int row = pbase + wm + mf * 16 + fq * 4 + jj;
        const unsigned int h0 = gelu_mul_bf16(acc[mf][0][jj], acc[mf][1][jj]);
        const unsigned int h1 = gelu_mul_bf16(acc[mf][2][jj], acc[mf][3][jj]);
        a32[(size_t)row * (I_DIM / 2) + cidx] = h0 | (h1 << 16);
      }
  } else {
    // plain bf16 stores of w*d into d_pair (combine sums the two experts)
#pragma unroll
    for (int mf = 0; mf < 4; ++mf)
#pragma unroll
      for (int jj = 0; jj < 4; ++jj) {
        const int prow = pbase + wm + mf * 16 + fq * 4 + jj;
        const float w = pair_weight[prow];
        unsigned short* dp = d_pair + (size_t)prow * H_DIM + nt * 256 + wn + fr;
#pragma unroll
        for (int nf = 0; nf < 4; ++nf)
          dp[nf * 16] = f2bf(w * acc[mf][nf][jj]);
      }
  }
}

// ========================= combine: out[t] = d[p0] + d[p1] =================
__global__ __launch_bounds__(256)
void combine(const unsigned short* __restrict__ d_pair,
             const int* __restrict__ inv,
             float* __restrict__ out) {
  const int tid = threadIdx.x;
  const int tok = blockIdx.x * 2 + (tid >> 7);
  const int ln = tid & 127;
  const int p0 = inv[2 * tok], p1 = inv[2 * tok + 1];
  const uint4* r0 = (const uint4*)(d_pair + (size_t)p0 * H_DIM);
  const uint4* r1 = (const uint4*)(d_pair + (size_t)p1 * H_DIM);
  float4* o = (float4*)(out + (size_t)tok * H_DIM);
#pragma unroll
  for (int j = 0; j < 2; ++j) {
    const int c = ln + j * 128;               // uint4 index, 256 per row
    const uint4 a = r0[c];
    const uint4 b = r1[c];
    float4 fa, fb;
    fa.x = bflo(a.x) + bflo(b.x); fa.y = bfhi(a.x) + bfhi(b.x);
    fa.z = bflo(a.y) + bflo(b.y); fa.w = bfhi(a.y) + bfhi(b.y);
    fb.x = bflo(a.z) + bflo(b.z); fb.y = bfhi(a.z) + bfhi(b.z);
    fb.z = bflo(a.w) + bflo(b.w); fb.w = bfhi(a.w) + bfhi(b.w);
    o[2 * c] = fa;
    o[2 * c + 1] = fb;
  }
}

// ================================= launch ==================================
extern "C" void kernel_launch(void* const* d_in, const int* in_sizes, int n_in,
                              void* d_out, int out_size, void* d_ws, size_t ws_size,
                              hipStream_t stream) {
  const float* x  = (const float*)d_in[0];
  const float* Wg = (const float*)d_in[1];
  const float* Wu = (const float*)d_in[2];
  const float* Wd = (const float*)d_in[3];
  const int*   sel = (const int*)d_in[4];
  const float* rw  = (const float*)d_in[5];
  float* out = (float*)d_out;

  char* base = (char*)d_ws;
  size_t off = 0;
  auto take = [&](size_t bytes) { char* p = base + off; off += bytes; return p; };
  unsigned short* xb     = (unsigned short*)take((size_t)T_TOK * H_DIM * 2);
  unsigned short* WguT   = (unsigned short*)take((size_t)E_NUM * 2048 * H_DIM * 2);
  unsigned short* WdT    = (unsigned short*)take((size_t)E_NUM * H_DIM * I_DIM * 2);
  unsigned short* a_pair = (unsigned short*)take((size_t)CAP * I_DIM * 2);
  unsigned short* d_pair = (unsigned short*)take((size_t)CAP * H_DIM * 2);
  int*   pair_token  = (int*)take(CAP * 4);
  float* pair_weight = (float*)take(CAP * 4);
  int*   inv         = (int*)take(NPAIR * 4);
  int*   tile_expert = (int*)take(512);
  int*   tile_pos    = (int*)take(512);
  (void)off;

  hipFuncSetAttribute((const void*)&moe_gemm<0>,
                      hipFuncAttributeMaxDynamicSharedMemorySize, 147456);
  hipFuncSetAttribute((const void*)&moe_gemm<1>,
                      hipFuncAttributeMaxDynamicSharedMemorySize, 147456);

  prep_all<<<PREP_BLKS, 512, 0, stream>>>(
      (const float4*)x, (ushort4*)xb, Wg, Wu, Wd, WguT, WdT, sel, rw,
      pair_token, pair_weight, inv, tile_expert, tile_pos);

  moe_gemm<0><<<NTB2, 512, 147456, stream>>>(
      xb, WguT, pair_token, pair_weight, tile_expert, tile_pos,
      (unsigned int*)a_pair, nullptr);

  moe_gemm<1><<<NTB2, 512, 147456, stream>>>(
      a_pair, WdT, pair_token, pair_weight, tile_expert, tile_pos,
      nullptr, d_pair);

  combine<<<T_TOK / 2, 256, 0, stream>>>(d_pair, inv, out);
}